// Round 1
// baseline (1492.905 us; speedup 1.0000x reference)
//
#include <hip/hip_runtime.h>

typedef __attribute__((ext_vector_type(8))) short short8;
typedef __attribute__((ext_vector_type(4))) float f32x4;
typedef unsigned int uint;
typedef unsigned short ushort;

#define T_ 256
#define B_ 16
#define D_ 256
#define H_ 512
#define V_ 32000
#define GH 2048   /* 4*H */

__device__ __forceinline__ ushort f2bf(float f) {
    uint u = __float_as_uint(f);
    u += 0x7FFFu + ((u >> 16) & 1u);
    return (ushort)(u >> 16);
}

__device__ __forceinline__ float fsig(float x) {
    return 1.0f / (1.0f + __expf(-x));
}

__device__ __forceinline__ float ftanh(float x) {
    float a = __expf(-2.0f * fabsf(x));
    float t = (1.0f - a) / (1.0f + a);
    return x >= 0.0f ? t : -t;
}

__device__ __forceinline__ void cvt4(const float* s, ushort* d) {
    float4 v = *(const float4*)s;
    ushort4 o;
    o.x = f2bf(v.x); o.y = f2bf(v.y); o.z = f2bf(v.z); o.w = f2bf(v.w);
    *(ushort4*)d = o;
}

// ---------------------------------------------------------------- prep ----
__global__ void prep_convert(const float* __restrict__ Wih, const float* __restrict__ Whh,
                             const float* __restrict__ Wfc, const float* __restrict__ bih,
                             const float* __restrict__ bhh,
                             ushort* __restrict__ dWih, ushort* __restrict__ dWhh,
                             ushort* __restrict__ dWfc, float* __restrict__ bsum) {
    const long nA = (long)GH * D_ / 4;       // 131072
    const long nB = (long)GH * H_ / 4;       // 262144
    const long nC = (long)V_ * H_ / 4;       // 4096000
    const long nS = GH / 4;                  // 512
    long i = (long)blockIdx.x * blockDim.x + threadIdx.x;
    if (i >= nA + nB + nC + nS) return;
    if (i < nA) {
        cvt4(Wih + i * 4, dWih + i * 4);
    } else if (i < nA + nB) {
        long j = i - nA;
        cvt4(Whh + j * 4, dWhh + j * 4);
    } else if (i < nA + nB + nC) {
        long j = i - nA - nB;
        cvt4(Wfc + j * 4, dWfc + j * 4);
    } else {
        long j = (i - nA - nB - nC) * 4;
        float4 a = *(const float4*)(bih + j);
        float4 b = *(const float4*)(bhh + j);
        float4 o;
        o.x = a.x + b.x; o.y = a.y + b.y; o.z = a.z + b.z; o.w = a.w + b.w;
        *(float4*)(bsum + j) = o;
    }
}

__global__ void prep_xseq(const float* __restrict__ images, const int* __restrict__ labels,
                          const float* __restrict__ embed, ushort* __restrict__ xseq) {
    int m = blockIdx.x;          // 0..4095  (t*16+b)
    int l = threadIdx.x;         // 0..63
    int t = m >> 4, b = m & 15;
    const float* src = (t == 0) ? (images + b * D_) : (embed + (long)labels[m] * D_);
    cvt4(src + l * 4, xseq + (long)m * D_ + l * 4);
}

// ------------------------------------------------- 128x128 bf16 GEMM ------
// C(M x N) = A(M x K) * B(N x K)^T + bias[n];  A,B bf16 K-major, C f32.
// grid: (M/128, N/128), m fastest for B-tile L2 reuse.
template <int K>
__global__ __launch_bounds__(256) void gemm_bt(const ushort* __restrict__ A,
                                               const ushort* __restrict__ Bw,
                                               float* __restrict__ C,
                                               const float* __restrict__ bias,
                                               int ldc) {
    __shared__ ushort As[128 * 64];
    __shared__ ushort Bs[128 * 64];
    const int tid = threadIdx.x;
    const int lane = tid & 63;
    const int w = tid >> 6;
    const int wr = w >> 1, wc = w & 1;
    const long mBase = (long)blockIdx.x * 128;
    const long nBase = (long)blockIdx.y * 128;

    f32x4 acc[4][4];
#pragma unroll
    for (int i = 0; i < 4; ++i)
#pragma unroll
        for (int j = 0; j < 4; ++j) acc[i][j] = (f32x4){0.f, 0.f, 0.f, 0.f};

    const char* Ab = (const char*)A;
    const char* Bb = (const char*)Bw;

    for (int kk = 0; kk < K / 64; ++kk) {
        // stage 16KB A + 16KB B; linear LDS dest, swizzle pre-applied on source
#pragma unroll
        for (int it = 0; it < 4; ++it) {
            int c = w * 4 + it;                 // chunk 0..15, wave-uniform
            int r = c * 8 + (lane >> 3);        // tile row 0..127
            int sg = (lane & 7) ^ (r & 7);      // source 16B granule
            long aoff = (mBase + r) * (long)(K * 2) + kk * 128 + sg * 16;
            long boff = (nBase + r) * (long)(K * 2) + kk * 128 + sg * 16;
            __builtin_amdgcn_global_load_lds(
                (const __attribute__((address_space(1))) void*)(Ab + aoff),
                (__attribute__((address_space(3))) void*)((char*)As + c * 1024), 16, 0, 0);
            __builtin_amdgcn_global_load_lds(
                (const __attribute__((address_space(1))) void*)(Bb + boff),
                (__attribute__((address_space(3))) void*)((char*)Bs + c * 1024), 16, 0, 0);
        }
        __syncthreads();
#pragma unroll
        for (int k2 = 0; k2 < 2; ++k2) {
            short8 af[4], bfr[4];
#pragma unroll
            for (int mi = 0; mi < 4; ++mi) {
                int mrow = wr * 64 + mi * 16 + (lane & 15);
                int g = (k2 * 4 + (lane >> 4)) ^ (mrow & 7);
                af[mi] = *(const short8*)((const char*)As + mrow * 128 + g * 16);
            }
#pragma unroll
            for (int ni = 0; ni < 4; ++ni) {
                int nrow = wc * 64 + ni * 16 + (lane & 15);
                int g = (k2 * 4 + (lane >> 4)) ^ (nrow & 7);
                bfr[ni] = *(const short8*)((const char*)Bs + nrow * 128 + g * 16);
            }
#pragma unroll
            for (int mi = 0; mi < 4; ++mi)
#pragma unroll
                for (int ni = 0; ni < 4; ++ni)
                    acc[mi][ni] = __builtin_amdgcn_mfma_f32_16x16x32_bf16(
                        af[mi], bfr[ni], acc[mi][ni], 0, 0, 0);
        }
        __syncthreads();
    }
    // epilogue: C row=(lane>>4)*4+rr, col=lane&15 within each 16x16 tile
#pragma unroll
    for (int ni = 0; ni < 4; ++ni) {
        long col = nBase + wc * 64 + ni * 16 + (lane & 15);
        float bv = bias[col];
#pragma unroll
        for (int mi = 0; mi < 4; ++mi) {
            long row0 = mBase + wr * 64 + mi * 16 + ((lane >> 4) << 2);
#pragma unroll
            for (int rr = 0; rr < 4; ++rr)
                C[(row0 + rr) * (long)ldc + col] = acc[mi][ni][rr] + bv;
        }
    }
}

// ------------------------------------------------------------- scan ------
// 32 persistent blocks; block g owns h columns [g*16, g*16+16).
// LDS: W slice 64x512 bf16 (swizzled) + full h 16x512 bf16 (swizzled) + gate xchg.
__global__ __launch_bounds__(256) void lstm_scan(const ushort* __restrict__ Whh,
                                                 const float* __restrict__ xg,
                                                 ushort* __restrict__ hs,
                                                 uint* __restrict__ flags) {
    __shared__ ushort Ws[64 * 512];   // 64 KB
    __shared__ ushort hb[16 * 512];   // 16 KB
    __shared__ float gb[4][16][16];   // 4 KB

    const int tid = threadIdx.x;
    const int lane = tid & 63;
    const int w = tid >> 6;
    const int g = blockIdx.x;

    // load W_hh slice: rows q*16+jj -> global row q*512 + g*16 + jj
#pragma unroll
    for (int j = 0; j < 16; ++j) {
        int gid = j * 256 + tid;       // granule id, 4096 total
        int row = gid >> 6;            // 0..63
        int gcol = gid & 63;           // 16B granule in row
        int srow = (row >> 4) * H_ + g * 16 + (row & 15);
        uint4 v = *(const uint4*)(Whh + (long)srow * H_ + gcol * 8);
        int dg = gcol ^ (row & 7);
        *(uint4*)((char*)Ws + row * 1024 + dg * 16) = v;
    }
    __syncthreads();

    const int b = tid >> 4;
    const int jj = tid & 15;
    float cst = 0.0f;

    for (int t = 0; t < T_; ++t) {
        if (t > 0) {
            // wait until every block published h(t-1)
            int fi = lane & 31;
            uint v = __hip_atomic_load(&flags[fi], __ATOMIC_RELAXED, __HIP_MEMORY_SCOPE_AGENT);
            int guard = 0;
            while (v < (uint)t) {
                __builtin_amdgcn_s_sleep(1);
                v = __hip_atomic_load(&flags[fi], __ATOMIC_RELAXED, __HIP_MEMORY_SCOPE_AGENT);
                if (++guard > (1 << 20)) break;  // deadlock bail (visible failure, no hang)
            }
            __syncthreads();
            __builtin_amdgcn_fence(__ATOMIC_ACQUIRE, "agent");
            // stage h(t-1): 16KB
            const ushort* hsrc = hs + (long)(t - 1) * (B_ * H_);
#pragma unroll
            for (int j = 0; j < 4; ++j) {
                int gid = j * 256 + tid;   // 0..1023
                int row = gid >> 6;        // 0..15
                int gcol = gid & 63;
                uint4 v2 = *(const uint4*)(hsrc + row * H_ + gcol * 8);
                int dg = gcol ^ (row & 7);
                *(uint4*)((char*)hb + row * 1024 + dg * 16) = v2;
            }
            __syncthreads();
            // wave w computes its gate-q 16x16 tile, K=512
            f32x4 acc = (f32x4){0.f, 0.f, 0.f, 0.f};
            const int arow = lane & 15;
            const int brow = w * 16 + (lane & 15);
#pragma unroll
            for (int k0 = 0; k0 < 16; ++k0) {
                int ga = (k0 * 4 + (lane >> 4)) ^ (arow & 7);
                int gB = (k0 * 4 + (lane >> 4)) ^ (brow & 7);
                short8 a = *(const short8*)((const char*)hb + arow * 1024 + ga * 16);
                short8 bb = *(const short8*)((const char*)Ws + brow * 1024 + gB * 16);
                acc = __builtin_amdgcn_mfma_f32_16x16x32_bf16(a, bb, acc, 0, 0, 0);
            }
#pragma unroll
            for (int r = 0; r < 4; ++r)
                gb[w][((lane >> 4) << 2) + r][lane & 15] = acc[r];
            __syncthreads();
        }
        // elementwise LSTM cell; thread owns (b, jj)
        long xb = ((long)t * B_ + b) * GH + g * 16 + jj;
        float gi = xg[xb];
        float gf = xg[xb + 512];
        float gg = xg[xb + 1024];
        float go = xg[xb + 1536];
        if (t > 0) {
            gi += gb[0][b][jj];
            gf += gb[1][b][jj];
            gg += gb[2][b][jj];
            go += gb[3][b][jj];
        }
        float ii = fsig(gi), ff = fsig(gf), oo = fsig(go), tg = ftanh(gg);
        cst = ff * cst + ii * tg;
        float hv = oo * ftanh(cst);
        hs[(long)t * (B_ * H_) + b * H_ + g * 16 + jj] = f2bf(hv);
        __syncthreads();   // drains vmcnt: all hs writes of this block complete
        if (tid == 0)
            __hip_atomic_store(&flags[g], (uint)(t + 1), __ATOMIC_RELEASE, __HIP_MEMORY_SCOPE_AGENT);
    }
}

// ---------------------------------------------------------------- host ----
extern "C" void kernel_launch(void* const* d_in, const int* in_sizes, int n_in,
                              void* d_out, int out_size, void* d_ws, size_t ws_size,
                              hipStream_t stream) {
    const float* images = (const float*)d_in[0];
    const int* labels   = (const int*)d_in[1];
    const float* embed  = (const float*)d_in[2];
    const float* Wih    = (const float*)d_in[3];
    const float* Whh    = (const float*)d_in[4];
    const float* bih    = (const float*)d_in[5];
    const float* bhh    = (const float*)d_in[6];
    const float* Wfc    = (const float*)d_in[7];
    const float* bfc    = (const float*)d_in[8];
    float* out = (float*)d_out;

    char* p = (char*)d_ws;
    ushort* dWfc = (ushort*)p; p += (long)V_ * H_ * 2;     // 32.77 MB
    ushort* dWih = (ushort*)p; p += (long)GH * D_ * 2;     // 1.05 MB
    ushort* dWhh = (ushort*)p; p += (long)GH * H_ * 2;     // 2.10 MB
    ushort* xseq = (ushort*)p; p += (long)T_ * B_ * D_ * 2;   // 2.10 MB
    float* xg    = (float*)p;  p += (long)T_ * B_ * GH * 4;   // 33.55 MB
    ushort* hs   = (ushort*)p; p += (long)T_ * B_ * H_ * 2;   // 4.19 MB
    float* bsum  = (float*)p;  p += GH * 4;
    uint* flags  = (uint*)p;   p += 256;

    hipMemsetAsync(flags, 0, 32 * sizeof(uint), stream);

    {
        long total = (long)GH * D_ / 4 + (long)GH * H_ / 4 + (long)V_ * H_ / 4 + GH / 4;
        int blocks = (int)((total + 255) / 256);
        prep_convert<<<blocks, 256, 0, stream>>>(Wih, Whh, Wfc, bih, bhh, dWih, dWhh, dWfc, bsum);
    }
    prep_xseq<<<T_ * B_, 64, 0, stream>>>(images, labels, embed, xseq);

    // x_gates: (4096 x 2048) = xseq (4096 x 256) * Wih^T + (b_ih+b_hh)
    gemm_bt<D_><<<dim3(32, 16), 256, 0, stream>>>(xseq, dWih, xg, bsum, GH);

    lstm_scan<<<32, 256, 0, stream>>>(dWhh, xg, hs, flags);

    // logits: (4096 x 32000) = hs (4096 x 512) * Wfc^T + b_fc
    gemm_bt<H_><<<dim3(32, 250), 256, 0, stream>>>(hs, dWfc, out, bfc, V_);
}

// Round 2
// 1030.838 us; speedup vs baseline: 1.4482x; 1.4482x over previous
//
#include <hip/hip_runtime.h>

typedef __attribute__((ext_vector_type(8))) short short8;
typedef __attribute__((ext_vector_type(4))) float f32x4;
typedef unsigned int uint;
typedef unsigned short ushort;

#define T_ 256
#define B_ 16
#define D_ 256
#define H_ 512
#define V_ 32000
#define GH 2048   /* 4*H */

__device__ __forceinline__ ushort f2bf(float f) {
    uint u = __float_as_uint(f);
    u += 0x7FFFu + ((u >> 16) & 1u);
    return (ushort)(u >> 16);
}

__device__ __forceinline__ float fsig(float x) {
    return 1.0f / (1.0f + __expf(-x));
}

__device__ __forceinline__ float ftanh(float x) {
    float a = __expf(-2.0f * fabsf(x));
    float t = (1.0f - a) / (1.0f + a);
    return x >= 0.0f ? t : -t;
}

__device__ __forceinline__ void cvt4(const float* s, ushort* d) {
    float4 v = *(const float4*)s;
    ushort4 o;
    o.x = f2bf(v.x); o.y = f2bf(v.y); o.z = f2bf(v.z); o.w = f2bf(v.w);
    *(ushort4*)d = o;
}

// ---------------------------------------------------------------- prep ----
__global__ void prep_convert(const float* __restrict__ Wih, const float* __restrict__ Whh,
                             const float* __restrict__ Wfc, const float* __restrict__ bih,
                             const float* __restrict__ bhh,
                             ushort* __restrict__ dWih, ushort* __restrict__ dWhh,
                             ushort* __restrict__ dWfc, float* __restrict__ bsum) {
    const long nA = (long)GH * D_ / 4;       // 131072
    const long nB = (long)GH * H_ / 4;       // 262144
    const long nC = (long)V_ * H_ / 4;       // 4096000
    const long nS = GH / 4;                  // 512
    long i = (long)blockIdx.x * blockDim.x + threadIdx.x;
    if (i >= nA + nB + nC + nS) return;
    if (i < nA) {
        cvt4(Wih + i * 4, dWih + i * 4);
    } else if (i < nA + nB) {
        long j = i - nA;
        cvt4(Whh + j * 4, dWhh + j * 4);
    } else if (i < nA + nB + nC) {
        long j = i - nA - nB;
        cvt4(Wfc + j * 4, dWfc + j * 4);
    } else {
        long j = (i - nA - nB - nC) * 4;
        float4 a = *(const float4*)(bih + j);
        float4 b = *(const float4*)(bhh + j);
        float4 o;
        o.x = a.x + b.x; o.y = a.y + b.y; o.z = a.z + b.z; o.w = a.w + b.w;
        *(float4*)(bsum + j) = o;
    }
}

__global__ void prep_xseq(const float* __restrict__ images, const int* __restrict__ labels,
                          const float* __restrict__ embed, ushort* __restrict__ xseq) {
    int m = blockIdx.x;          // 0..4095  (t*16+b)
    int l = threadIdx.x;         // 0..63
    int t = m >> 4, b = m & 15;
    const float* src = (t == 0) ? (images + b * D_) : (embed + (long)labels[m] * D_);
    cvt4(src + l * 4, xseq + (long)m * D_ + l * 4);
}

// ------------------------------------------------- 128x128 bf16 GEMM ------
// C(M x N) = A(M x K) * B(N x K)^T + bias[n];  A,B bf16 K-major, C f32.
// grid: (M/128, N/128), m fastest for B-tile L2 reuse.
template <int K>
__global__ __launch_bounds__(256) void gemm_bt(const ushort* __restrict__ A,
                                               const ushort* __restrict__ Bw,
                                               float* __restrict__ C,
                                               const float* __restrict__ bias,
                                               int ldc) {
    __shared__ ushort As[128 * 64];
    __shared__ ushort Bs[128 * 64];
    const int tid = threadIdx.x;
    const int lane = tid & 63;
    const int w = tid >> 6;
    const int wr = w >> 1, wc = w & 1;
    const long mBase = (long)blockIdx.x * 128;
    const long nBase = (long)blockIdx.y * 128;

    f32x4 acc[4][4];
#pragma unroll
    for (int i = 0; i < 4; ++i)
#pragma unroll
        for (int j = 0; j < 4; ++j) acc[i][j] = (f32x4){0.f, 0.f, 0.f, 0.f};

    const char* Ab = (const char*)A;
    const char* Bb = (const char*)Bw;

    for (int kk = 0; kk < K / 64; ++kk) {
        // stage 16KB A + 16KB B; linear LDS dest, swizzle pre-applied on source
#pragma unroll
        for (int it = 0; it < 4; ++it) {
            int c = w * 4 + it;                 // chunk 0..15, wave-uniform
            int r = c * 8 + (lane >> 3);        // tile row 0..127
            int sg = (lane & 7) ^ (r & 7);      // source 16B granule
            long aoff = (mBase + r) * (long)(K * 2) + kk * 128 + sg * 16;
            long boff = (nBase + r) * (long)(K * 2) + kk * 128 + sg * 16;
            __builtin_amdgcn_global_load_lds(
                (const __attribute__((address_space(1))) void*)(Ab + aoff),
                (__attribute__((address_space(3))) void*)((char*)As + c * 1024), 16, 0, 0);
            __builtin_amdgcn_global_load_lds(
                (const __attribute__((address_space(1))) void*)(Bb + boff),
                (__attribute__((address_space(3))) void*)((char*)Bs + c * 1024), 16, 0, 0);
        }
        __syncthreads();
#pragma unroll
        for (int k2 = 0; k2 < 2; ++k2) {
            short8 af[4], bfr[4];
#pragma unroll
            for (int mi = 0; mi < 4; ++mi) {
                int mrow = wr * 64 + mi * 16 + (lane & 15);
                int g = (k2 * 4 + (lane >> 4)) ^ (mrow & 7);
                af[mi] = *(const short8*)((const char*)As + mrow * 128 + g * 16);
            }
#pragma unroll
            for (int ni = 0; ni < 4; ++ni) {
                int nrow = wc * 64 + ni * 16 + (lane & 15);
                int g = (k2 * 4 + (lane >> 4)) ^ (nrow & 7);
                bfr[ni] = *(const short8*)((const char*)Bs + nrow * 128 + g * 16);
            }
#pragma unroll
            for (int mi = 0; mi < 4; ++mi)
#pragma unroll
                for (int ni = 0; ni < 4; ++ni)
                    acc[mi][ni] = __builtin_amdgcn_mfma_f32_16x16x32_bf16(
                        af[mi], bfr[ni], acc[mi][ni], 0, 0, 0);
        }
        __syncthreads();
    }
    // epilogue: C row=(lane>>4)*4+rr, col=lane&15 within each 16x16 tile
#pragma unroll
    for (int ni = 0; ni < 4; ++ni) {
        long col = nBase + wc * 64 + ni * 16 + (lane & 15);
        float bv = bias[col];
#pragma unroll
        for (int mi = 0; mi < 4; ++mi) {
            long row0 = mBase + wr * 64 + mi * 16 + ((lane >> 4) << 2);
#pragma unroll
            for (int rr = 0; rr < 4; ++rr)
                C[(row0 + rr) * (long)ldc + col] = acc[mi][ni][rr] + bv;
        }
    }
}

// ------------------------------------------------------------- scan ------
// 32 persistent blocks; block g owns h columns [g*16, g*16+16).
// Cross-block exchange exclusively via relaxed agent-scope atomics (sc0/sc1,
// coherence-point resident) — NO acquire/release fences (no buffer_wbl2 /
// buffer_inv L2 walks, which dominated R1's 4.6 us/step).
__global__ __launch_bounds__(256) void lstm_scan(const ushort* __restrict__ Whh,
                                                 const float* __restrict__ xg,
                                                 ushort* __restrict__ hs,
                                                 uint* __restrict__ flags) {
    __shared__ ushort Ws[64 * 512];   // 64 KB
    __shared__ ushort hb[16 * 512];   // 16 KB
    __shared__ float gb[4][16][16];   // 4 KB
    __shared__ ushort hloc[16][16];   // 512 B

    const int tid = threadIdx.x;
    const int lane = tid & 63;
    const int w = tid >> 6;
    const int g = blockIdx.x;

    // load W_hh slice: rows q*16+jj -> global row q*512 + g*16 + jj
#pragma unroll
    for (int j = 0; j < 16; ++j) {
        int gid = j * 256 + tid;       // granule id, 4096 total
        int row = gid >> 6;            // 0..63
        int gcol = gid & 63;           // 16B granule in row
        int srow = (row >> 4) * H_ + g * 16 + (row & 15);
        uint4 v = *(const uint4*)(Whh + (long)srow * H_ + gcol * 8);
        int dg = gcol ^ (row & 7);
        *(uint4*)((char*)Ws + row * 1024 + dg * 16) = v;
    }
    __syncthreads();

    const int b = tid >> 4;
    const int jj = tid & 15;
    float cst = 0.0f;

    for (int t = 0; t < T_; ++t) {
        // prefetch this step's input-side gates (independent of h) before the wait
        long xb = ((long)t * B_ + b) * GH + g * 16 + jj;
        float gi = xg[xb];
        float gf = xg[xb + 512];
        float gg = xg[xb + 1024];
        float go = xg[xb + 1536];

        if (t > 0) {
            // wait until every block published h(t-1)
            int fi = lane & 31;
            uint v = __hip_atomic_load(&flags[fi], __ATOMIC_RELAXED, __HIP_MEMORY_SCOPE_AGENT);
            int guard = 0;
            while (v < (uint)t) {
                __builtin_amdgcn_s_sleep(1);
                v = __hip_atomic_load(&flags[fi], __ATOMIC_RELAXED, __HIP_MEMORY_SCOPE_AGENT);
                if (++guard > (1 << 20)) break;  // deadlock bail (visible failure, no hang)
            }
            // stage h(t-1) into LDS via coherence-point loads (no fence needed:
            // producer vmcnt(0)-ordered its sc1 data stores before the sc1 flag)
            const uint* hsrcU = (const uint*)hs + ((long)(t - 1) * (B_ * H_)) / 2;
            const int row = tid >> 4;          // batch row 0..15
            const int c0 = tid & 15;
            uint vals[16];
#pragma unroll
            for (int j2 = 0; j2 < 16; ++j2)
                vals[j2] = __hip_atomic_load((uint*)(hsrcU + row * 256 + c0 + j2 * 16),
                                             __ATOMIC_RELAXED, __HIP_MEMORY_SCOPE_AGENT);
#pragma unroll
            for (int j2 = 0; j2 < 16; ++j2) {
                int u = c0 + j2 * 16;          // uint index within row, 0..255
                int gcol = u >> 2, sub = u & 3;
                int dg = gcol ^ (row & 7);
                *(uint*)((char*)hb + row * 1024 + dg * 16 + sub * 4) = vals[j2];
            }
            __syncthreads();
            // wave w computes its gate-q 16x16 tile, K=512, 2 accumulators
            f32x4 acc0 = (f32x4){0.f, 0.f, 0.f, 0.f};
            f32x4 acc1 = (f32x4){0.f, 0.f, 0.f, 0.f};
            const int arow = lane & 15;
            const int brow = w * 16 + (lane & 15);
#pragma unroll
            for (int k0 = 0; k0 < 16; k0 += 2) {
                int ga0 = (k0 * 4 + (lane >> 4)) ^ (arow & 7);
                int gB0 = (k0 * 4 + (lane >> 4)) ^ (brow & 7);
                int ga1 = ((k0 + 1) * 4 + (lane >> 4)) ^ (arow & 7);
                int gB1 = ((k0 + 1) * 4 + (lane >> 4)) ^ (brow & 7);
                short8 a0 = *(const short8*)((const char*)hb + arow * 1024 + ga0 * 16);
                short8 b0 = *(const short8*)((const char*)Ws + brow * 1024 + gB0 * 16);
                short8 a1 = *(const short8*)((const char*)hb + arow * 1024 + ga1 * 16);
                short8 b1 = *(const short8*)((const char*)Ws + brow * 1024 + gB1 * 16);
                acc0 = __builtin_amdgcn_mfma_f32_16x16x32_bf16(a0, b0, acc0, 0, 0, 0);
                acc1 = __builtin_amdgcn_mfma_f32_16x16x32_bf16(a1, b1, acc1, 0, 0, 0);
            }
#pragma unroll
            for (int r = 0; r < 4; ++r)
                gb[w][((lane >> 4) << 2) + r][lane & 15] = acc0[r] + acc1[r];
            __syncthreads();
            gi += gb[0][b][jj];
            gf += gb[1][b][jj];
            gg += gb[2][b][jj];
            go += gb[3][b][jj];
        }
        // elementwise LSTM cell; thread owns (b, jj)
        float ii = fsig(gi), ff = fsig(gf), oo = fsig(go), tg = ftanh(gg);
        cst = ff * cst + ii * tg;
        float hv = oo * ftanh(cst);
        hloc[b][jj] = f2bf(hv);
        __syncthreads();
        // publish h slice via coherence-point stores (uint = 2 bf16)
        if (tid < 128) {
            int bb = tid >> 3, u = tid & 7;
            uint val = (uint)hloc[bb][u * 2] | ((uint)hloc[bb][u * 2 + 1] << 16);
            uint* dst = (uint*)hs + (((long)t * B_ + bb) * H_ + g * 16) / 2 + u;
            __hip_atomic_store(dst, val, __ATOMIC_RELAXED, __HIP_MEMORY_SCOPE_AGENT);
        }
        asm volatile("s_waitcnt vmcnt(0)" ::: "memory");
        __syncthreads();   // all waves' stores acked at coherence point
        if (tid == 0)
            __hip_atomic_store(&flags[g], (uint)(t + 1), __ATOMIC_RELAXED, __HIP_MEMORY_SCOPE_AGENT);
    }
}

// ---------------------------------------------------------------- host ----
extern "C" void kernel_launch(void* const* d_in, const int* in_sizes, int n_in,
                              void* d_out, int out_size, void* d_ws, size_t ws_size,
                              hipStream_t stream) {
    const float* images = (const float*)d_in[0];
    const int* labels   = (const int*)d_in[1];
    const float* embed  = (const float*)d_in[2];
    const float* Wih    = (const float*)d_in[3];
    const float* Whh    = (const float*)d_in[4];
    const float* bih    = (const float*)d_in[5];
    const float* bhh    = (const float*)d_in[6];
    const float* Wfc    = (const float*)d_in[7];
    const float* bfc    = (const float*)d_in[8];
    float* out = (float*)d_out;

    char* p = (char*)d_ws;
    ushort* dWfc = (ushort*)p; p += (long)V_ * H_ * 2;     // 32.77 MB
    ushort* dWih = (ushort*)p; p += (long)GH * D_ * 2;     // 1.05 MB
    ushort* dWhh = (ushort*)p; p += (long)GH * H_ * 2;     // 2.10 MB
    ushort* xseq = (ushort*)p; p += (long)T_ * B_ * D_ * 2;   // 2.10 MB
    float* xg    = (float*)p;  p += (long)T_ * B_ * GH * 4;   // 33.55 MB
    ushort* hs   = (ushort*)p; p += (long)T_ * B_ * H_ * 2;   // 4.19 MB
    float* bsum  = (float*)p;  p += GH * 4;
    uint* flags  = (uint*)p;   p += 256;

    hipMemsetAsync(flags, 0, 32 * sizeof(uint), stream);

    {
        long total = (long)GH * D_ / 4 + (long)GH * H_ / 4 + (long)V_ * H_ / 4 + GH / 4;
        int blocks = (int)((total + 255) / 256);
        prep_convert<<<blocks, 256, 0, stream>>>(Wih, Whh, Wfc, bih, bhh, dWih, dWhh, dWfc, bsum);
    }
    prep_xseq<<<T_ * B_, 64, 0, stream>>>(images, labels, embed, xseq);

    // x_gates: (4096 x 2048) = xseq (4096 x 256) * Wih^T + (b_ih+b_hh)
    gemm_bt<D_><<<dim3(32, 16), 256, 0, stream>>>(xseq, dWih, xg, bsum, GH);

    lstm_scan<<<32, 256, 0, stream>>>(dWhh, xg, hs, flags);

    // logits: (4096 x 32000) = hs (4096 x 512) * Wfc^T + b_fc
    gemm_bt<H_><<<dim3(32, 250), 256, 0, stream>>>(hs, dWfc, out, bfc, V_);
}

// Round 3
// 897.400 us; speedup vs baseline: 1.6636x; 1.1487x over previous
//
#include <hip/hip_runtime.h>

typedef __attribute__((ext_vector_type(8))) short short8;
typedef __attribute__((ext_vector_type(4))) float f32x4;
typedef unsigned int uint;
typedef unsigned short ushort;

#define T_ 256
#define B_ 16
#define D_ 256
#define H_ 512
#define V_ 32000
#define GH 2048   /* 4*H */
#define SENT 0xFFFFFFFFu

__device__ __forceinline__ ushort f2bf(float f) {
    uint u = __float_as_uint(f);
    u += 0x7FFFu + ((u >> 16) & 1u);
    return (ushort)(u >> 16);
}

__device__ __forceinline__ float fsig(float x) {
    return 1.0f / (1.0f + __expf(-x));
}

__device__ __forceinline__ float ftanh(float x) {
    float a = __expf(-2.0f * fabsf(x));
    float t = (1.0f - a) / (1.0f + a);
    return x >= 0.0f ? t : -t;
}

__device__ __forceinline__ void cvt4(const float* s, ushort* d) {
    float4 v = *(const float4*)s;
    ushort4 o;
    o.x = f2bf(v.x); o.y = f2bf(v.y); o.z = f2bf(v.z); o.w = f2bf(v.w);
    *(ushort4*)d = o;
}

// ---------------------------------------------------------------- prep ----
__global__ void prep_convert(const float* __restrict__ Wih, const float* __restrict__ Whh,
                             const float* __restrict__ Wfc, const float* __restrict__ bih,
                             const float* __restrict__ bhh,
                             ushort* __restrict__ dWih, ushort* __restrict__ dWhh,
                             ushort* __restrict__ dWfc, float* __restrict__ bsum) {
    const long nA = (long)GH * D_ / 4;       // 131072
    const long nB = (long)GH * H_ / 4;       // 262144
    const long nC = (long)V_ * H_ / 4;       // 4096000
    const long nS = GH / 4;                  // 512
    long i = (long)blockIdx.x * blockDim.x + threadIdx.x;
    if (i >= nA + nB + nC + nS) return;
    if (i < nA) {
        cvt4(Wih + i * 4, dWih + i * 4);
    } else if (i < nA + nB) {
        long j = i - nA;
        cvt4(Whh + j * 4, dWhh + j * 4);
    } else if (i < nA + nB + nC) {
        long j = i - nA - nB;
        cvt4(Wfc + j * 4, dWfc + j * 4);
    } else {
        long j = (i - nA - nB - nC) * 4;
        float4 a = *(const float4*)(bih + j);
        float4 b = *(const float4*)(bhh + j);
        float4 o;
        o.x = a.x + b.x; o.y = a.y + b.y; o.z = a.z + b.z; o.w = a.w + b.w;
        *(float4*)(bsum + j) = o;
    }
}

__global__ void prep_xseq(const float* __restrict__ images, const int* __restrict__ labels,
                          const float* __restrict__ embed, ushort* __restrict__ xseq) {
    int m = blockIdx.x;          // 0..4095  (t*16+b)
    int l = threadIdx.x;         // 0..63
    int t = m >> 4, b = m & 15;
    const float* src = (t == 0) ? (images + b * D_) : (embed + (long)labels[m] * D_);
    cvt4(src + l * 4, xseq + (long)m * D_ + l * 4);
}

// ------------------------------------------------- 128x128 bf16 GEMM ------
// C(M x N) = A(M x K) * B(N x K)^T + bias[n];  A,B bf16 K-major, C f32.
// grid: (M/128, N/128), m fastest for B-tile L2 reuse.
template <int K>
__global__ __launch_bounds__(256) void gemm_bt(const ushort* __restrict__ A,
                                               const ushort* __restrict__ Bw,
                                               float* __restrict__ C,
                                               const float* __restrict__ bias,
                                               int ldc) {
    __shared__ ushort As[128 * 64];
    __shared__ ushort Bs[128 * 64];
    const int tid = threadIdx.x;
    const int lane = tid & 63;
    const int w = tid >> 6;
    const int wr = w >> 1, wc = w & 1;
    const long mBase = (long)blockIdx.x * 128;
    const long nBase = (long)blockIdx.y * 128;

    f32x4 acc[4][4];
#pragma unroll
    for (int i = 0; i < 4; ++i)
#pragma unroll
        for (int j = 0; j < 4; ++j) acc[i][j] = (f32x4){0.f, 0.f, 0.f, 0.f};

    const char* Ab = (const char*)A;
    const char* Bb = (const char*)Bw;

    for (int kk = 0; kk < K / 64; ++kk) {
        // stage 16KB A + 16KB B; linear LDS dest, swizzle pre-applied on source
#pragma unroll
        for (int it = 0; it < 4; ++it) {
            int c = w * 4 + it;                 // chunk 0..15, wave-uniform
            int r = c * 8 + (lane >> 3);        // tile row 0..127
            int sg = (lane & 7) ^ (r & 7);      // source 16B granule
            long aoff = (mBase + r) * (long)(K * 2) + kk * 128 + sg * 16;
            long boff = (nBase + r) * (long)(K * 2) + kk * 128 + sg * 16;
            __builtin_amdgcn_global_load_lds(
                (const __attribute__((address_space(1))) void*)(Ab + aoff),
                (__attribute__((address_space(3))) void*)((char*)As + c * 1024), 16, 0, 0);
            __builtin_amdgcn_global_load_lds(
                (const __attribute__((address_space(1))) void*)(Bb + boff),
                (__attribute__((address_space(3))) void*)((char*)Bs + c * 1024), 16, 0, 0);
        }
        __syncthreads();
#pragma unroll
        for (int k2 = 0; k2 < 2; ++k2) {
            short8 af[4], bfr[4];
#pragma unroll
            for (int mi = 0; mi < 4; ++mi) {
                int mrow = wr * 64 + mi * 16 + (lane & 15);
                int g = (k2 * 4 + (lane >> 4)) ^ (mrow & 7);
                af[mi] = *(const short8*)((const char*)As + mrow * 128 + g * 16);
            }
#pragma unroll
            for (int ni = 0; ni < 4; ++ni) {
                int nrow = wc * 64 + ni * 16 + (lane & 15);
                int g = (k2 * 4 + (lane >> 4)) ^ (nrow & 7);
                bfr[ni] = *(const short8*)((const char*)Bs + nrow * 128 + g * 16);
            }
#pragma unroll
            for (int mi = 0; mi < 4; ++mi)
#pragma unroll
                for (int ni = 0; ni < 4; ++ni)
                    acc[mi][ni] = __builtin_amdgcn_mfma_f32_16x16x32_bf16(
                        af[mi], bfr[ni], acc[mi][ni], 0, 0, 0);
        }
        __syncthreads();
    }
    // epilogue: C row=(lane>>4)*4+rr, col=lane&15 within each 16x16 tile
#pragma unroll
    for (int ni = 0; ni < 4; ++ni) {
        long col = nBase + wc * 64 + ni * 16 + (lane & 15);
        float bv = bias[col];
#pragma unroll
        for (int mi = 0; mi < 4; ++mi) {
            long row0 = mBase + wr * 64 + mi * 16 + ((lane >> 4) << 2);
#pragma unroll
            for (int rr = 0; rr < 4; ++rr)
                C[(row0 + rr) * (long)ldc + col] = acc[mi][ni][rr] + bv;
        }
    }
}

// ------------------------------------------------------------- scan ------
// 32 persistent blocks; block g owns h columns [g*16, g*16+16).
// Sentinel protocol: hs pre-filled with 0xFFFFFFFF (bf16 NaN pair, unreachable
// for h = o*tanh(c) in (-1,1)). Producers store h words relaxed-agent (no ack,
// no flag); consumers spin-reload only still-sentinel words. One-way latency.
__global__ __launch_bounds__(256) void lstm_scan(const ushort* __restrict__ Whh,
                                                 const float* __restrict__ xg,
                                                 ushort* __restrict__ hs) {
    __shared__ ushort Ws[64 * 512];   // 64 KB
    __shared__ ushort hb[16 * 512];   // 16 KB
    __shared__ float gb[4][16][16];   // 4 KB
    __shared__ ushort hloc[16][16];   // 512 B

    const int tid = threadIdx.x;
    const int lane = tid & 63;
    const int w = tid >> 6;
    const int g = blockIdx.x;

    // load W_hh slice: rows q*16+jj -> global row q*512 + g*16 + jj
#pragma unroll
    for (int j = 0; j < 16; ++j) {
        int gid = j * 256 + tid;       // granule id, 4096 total
        int row = gid >> 6;            // 0..63
        int gcol = gid & 63;           // 16B granule in row
        int srow = (row >> 4) * H_ + g * 16 + (row & 15);
        uint4 v = *(const uint4*)(Whh + (long)srow * H_ + gcol * 8);
        int dg = gcol ^ (row & 7);
        *(uint4*)((char*)Ws + row * 1024 + dg * 16) = v;
    }
    __syncthreads();

    const int b = tid >> 4;
    const int jj = tid & 15;
    const int row = tid >> 4;          // consumer h-row (batch)
    const int c0 = tid & 15;
    float cst = 0.0f;

    for (int t = 0; t < T_; ++t) {
        // prefetch this step's input-side gates (independent of h) before the wait
        long xb = ((long)t * B_ + b) * GH + g * 16 + jj;
        float gi = xg[xb];
        float gf = xg[xb + 512];
        float gg = xg[xb + 1024];
        float go = xg[xb + 1536];

        if (t > 0) {
            // gather h(t-1) row: 16 uints, self-owned words from LDS
            uint vals[16];
#pragma unroll
            for (int j = 0; j < 16; ++j) {
                int u = c0 + j * 16;
                if ((u >> 3) == g)
                    vals[j] = (uint)hloc[row][(u & 7) * 2] |
                              ((uint)hloc[row][(u & 7) * 2 + 1] << 16);
                else
                    vals[j] = SENT;
            }
            uint* hsrcU = (uint*)hs + ((long)(t - 1) * (B_ * H_)) / 2 + row * 256;
            int guard = 0;
            for (;;) {
                int pend = 0;
#pragma unroll
                for (int j = 0; j < 16; ++j) {
                    if (vals[j] == SENT)
                        vals[j] = __hip_atomic_load(hsrcU + c0 + j * 16,
                                                    __ATOMIC_RELAXED, __HIP_MEMORY_SCOPE_AGENT);
                }
#pragma unroll
                for (int j = 0; j < 16; ++j) pend += (vals[j] == SENT) ? 1 : 0;
                if (pend == 0 || ++guard > (1 << 20)) break;
            }
            // scatter into swizzled LDS h-tile
#pragma unroll
            for (int j = 0; j < 16; ++j) {
                int u = c0 + j * 16;           // uint index within row, 0..255
                int gcol = u >> 2, sub = u & 3;
                int dg = gcol ^ (row & 7);
                *(uint*)((char*)hb + row * 1024 + dg * 16 + sub * 4) = vals[j];
            }
            __syncthreads();
            // wave w computes its gate-q 16x16 tile, K=512, 2 accumulators
            f32x4 acc0 = (f32x4){0.f, 0.f, 0.f, 0.f};
            f32x4 acc1 = (f32x4){0.f, 0.f, 0.f, 0.f};
            const int arow = lane & 15;
            const int brow = w * 16 + (lane & 15);
#pragma unroll
            for (int k0 = 0; k0 < 16; k0 += 2) {
                int ga0 = (k0 * 4 + (lane >> 4)) ^ (arow & 7);
                int gB0 = (k0 * 4 + (lane >> 4)) ^ (brow & 7);
                int ga1 = ((k0 + 1) * 4 + (lane >> 4)) ^ (arow & 7);
                int gB1 = ((k0 + 1) * 4 + (lane >> 4)) ^ (brow & 7);
                short8 a0 = *(const short8*)((const char*)hb + arow * 1024 + ga0 * 16);
                short8 b0 = *(const short8*)((const char*)Ws + brow * 1024 + gB0 * 16);
                short8 a1 = *(const short8*)((const char*)hb + arow * 1024 + ga1 * 16);
                short8 b1 = *(const short8*)((const char*)Ws + brow * 1024 + gB1 * 16);
                acc0 = __builtin_amdgcn_mfma_f32_16x16x32_bf16(a0, b0, acc0, 0, 0, 0);
                acc1 = __builtin_amdgcn_mfma_f32_16x16x32_bf16(a1, b1, acc1, 0, 0, 0);
            }
#pragma unroll
            for (int r = 0; r < 4; ++r)
                gb[w][((lane >> 4) << 2) + r][lane & 15] = acc0[r] + acc1[r];
            __syncthreads();
            gi += gb[0][b][jj];
            gf += gb[1][b][jj];
            gg += gb[2][b][jj];
            go += gb[3][b][jj];
        }
        // elementwise LSTM cell; thread owns (b, jj)
        float ii = fsig(gi), ff = fsig(gf), oo = fsig(go), tg = ftanh(gg);
        cst = ff * cst + ii * tg;
        float hv = oo * ftanh(cst);
        ushort hb16 = f2bf(hv);
        hloc[b][jj] = hb16;                       // self-fill source for t+1
        uint mybits = (uint)hb16;
        uint partner = (uint)__shfl_xor((int)mybits, 1);
        if ((jj & 1) == 0) {
            uint val = mybits | (partner << 16);
            uint* dst = (uint*)hs + ((long)t * B_ + b) * (H_ / 2) + (g * 16 + jj) / 2;
            __hip_atomic_store(dst, val, __ATOMIC_RELAXED, __HIP_MEMORY_SCOPE_AGENT);
        }
        __syncthreads();   // hloc visible to all before next step's self-fill
    }
}

// ---------------------------------------------------------------- host ----
extern "C" void kernel_launch(void* const* d_in, const int* in_sizes, int n_in,
                              void* d_out, int out_size, void* d_ws, size_t ws_size,
                              hipStream_t stream) {
    const float* images = (const float*)d_in[0];
    const int* labels   = (const int*)d_in[1];
    const float* embed  = (const float*)d_in[2];
    const float* Wih    = (const float*)d_in[3];
    const float* Whh    = (const float*)d_in[4];
    const float* bih    = (const float*)d_in[5];
    const float* bhh    = (const float*)d_in[6];
    const float* Wfc    = (const float*)d_in[7];
    const float* bfc    = (const float*)d_in[8];
    float* out = (float*)d_out;

    char* p = (char*)d_ws;
    ushort* dWfc = (ushort*)p; p += (long)V_ * H_ * 2;     // 32.77 MB
    ushort* dWih = (ushort*)p; p += (long)GH * D_ * 2;     // 1.05 MB
    ushort* dWhh = (ushort*)p; p += (long)GH * H_ * 2;     // 2.10 MB
    ushort* xseq = (ushort*)p; p += (long)T_ * B_ * D_ * 2;   // 2.10 MB
    float* xg    = (float*)p;  p += (long)T_ * B_ * GH * 4;   // 33.55 MB
    ushort* hs   = (ushort*)p; p += (long)T_ * B_ * H_ * 2;   // 4.19 MB
    float* bsum  = (float*)p;  p += GH * 4;

    // sentinel-fill hs each launch (0xFF bytes = bf16 NaN pairs); dispatch-
    // boundary release flushes it to the coherence point before the scan.
    hipMemsetAsync(hs, 0xFF, (size_t)T_ * B_ * H_ * 2, stream);

    {
        long total = (long)GH * D_ / 4 + (long)GH * H_ / 4 + (long)V_ * H_ / 4 + GH / 4;
        int blocks = (int)((total + 255) / 256);
        prep_convert<<<blocks, 256, 0, stream>>>(Wih, Whh, Wfc, bih, bhh, dWih, dWhh, dWfc, bsum);
    }
    prep_xseq<<<T_ * B_, 64, 0, stream>>>(images, labels, embed, xseq);

    // x_gates: (4096 x 2048) = xseq (4096 x 256) * Wih^T + (b_ih+b_hh)
    gemm_bt<D_><<<dim3(32, 16), 256, 0, stream>>>(xseq, dWih, xg, bsum, GH);

    lstm_scan<<<32, 256, 0, stream>>>(dWhh, xg, hs);

    // logits: (4096 x 32000) = hs (4096 x 512) * Wfc^T + b_fc
    gemm_bt<H_><<<dim3(32, 250), 256, 0, stream>>>(hs, dWfc, out, bfc, V_);
}